// Round 3
// baseline (125.957 us; speedup 1.0000x reference)
//
#include <hip/hip_runtime.h>
#include <hip/hip_cooperative_groups.h>
#include <stdint.h>

namespace cg = cooperative_groups;

// Problem constants: B=8, C=256, K=64, T=1000
constexpr int Bn  = 8;
constexpr int Cn  = 256;
constexpr int Kn  = 64;
constexpr int Tn  = 1000;
constexpr int CH  = 32;    // t per block (T padded to 1024)
constexpr int NCH = 32;    // chunks per b

constexpr int XT_P = 264;  // xT[t][c]  bf16 pitch (rows 16B-aligned)
constexpr int XC_P = 40;   // xc[c][t]  bf16 pitch (rows 16B-aligned)
constexpr int MW_P = 33;   // Mw[k][t]  f32 pitch (bank-friendly)
constexpr int WL_P = 40;   // wl[k][t]  bf16 pitch

typedef float f32x4 __attribute__((ext_vector_type(4)));
typedef __bf16 bf16x8 __attribute__((ext_vector_type(8)));

__device__ __forceinline__ unsigned short f2bf(float f) {
    unsigned u = __float_as_uint(f);
    return (unsigned short)((u + 0x7FFFu + ((u >> 16) & 1u)) >> 16);  // RNE
}

union BF8 { unsigned short u[8]; bf16x8 v; };

// ---------------------------------------------------------------------------
// Single cooperative kernel: grid (b x 32 chunks of 32t) = 256 blocks,
// 512 thr (8 waves, 1 block/CU — trivially co-resident for grid.sync()).
// Static LDS = 61.9 KB (< 64 KB limit).
// Phase 1 (verbatim from the passing round-2 lde_wp):
//   stage x f32->bf16 into xT[t][c] AND xc[c][t] (+fp32 xsq partials);
//   M-GEMM wave->(k-tile,t-tile), codes fp32 direct from global (L2-res),
//   exact fp32 csq; softmax over k in fp32; w -> wl bf16 (LDS) + Sp;
//   pool: one mfma per 16x16 tile contracts the 32-t chunk -> part.
// grid.sync()  (CG: device-scope fences handle cross-XCD part visibility)
// Phase 2: block handles 2 (b,k) pairs (tid>>8 = pair): sum 32 chunk
//   partials (cache-warm), subtract codes*S, 1/T, l2-normalize over c.
// ---------------------------------------------------------------------------
__global__ __launch_bounds__(512, 2) void lde_all(
    const float* __restrict__ x,            // (B, C, T)
    const float* __restrict__ codes,        // (C, K)
    const float* __restrict__ scales,       // (K)
    float* __restrict__ part,               // (B, NCH, K, C)
    float* __restrict__ Sp,                 // (B, K, NCH)
    float* __restrict__ out)                // (B, K, C)
{
    __shared__ __align__(16) unsigned short xT[CH * XT_P];   // 16896 B
    __shared__ __align__(16) unsigned short xc[Cn * XC_P];   // 20480 B
    __shared__ __align__(16) unsigned short wl[Kn * WL_P];   //  5120 B
    __shared__ float Mw[Kn * MW_P];                          //  8448 B
    __shared__ float xsqp[64 * 33];                          //  8448 B
    __shared__ float xsq[CH];                                //   128 B
    __shared__ float csqs[Kn];                               //   256 B
    __shared__ float spw[8 * 64];                            //  2048 B
    __shared__ float red2[8];                                //    32 B

    const int tid  = threadIdx.x;
    const int wave = tid >> 6;
    const int lane = tid & 63;
    const int n    = lane & 15;
    const int q    = lane >> 4;
    const int b    = blockIdx.x >> 5;
    const int ch   = blockIdx.x & 31;
    const int t0   = ch * CH;
    const float sc = scales[lane];           // lane = k in softmax phase

    // --- x staging: 512 threads, thread = (cg, tf); c = cg + 64r ---
    {
        const int tf = tid & 7;              // t-quad: t = t0 + 4*tf + i
        const int cg = tid >> 3;             // 0..63
        const float* xb = x + (size_t)b * Cn * Tn;
        float s0 = 0.f, s1 = 0.f, s2 = 0.f, s3 = 0.f;
        const int t = t0 + 4 * tf;
#pragma unroll
        for (int r = 0; r < 4; ++r) {
            int c = cg + 64 * r;
            float4 v;
            if (t + 3 < Tn) {
                v = *(const float4*)(xb + (size_t)c * Tn + t);
            } else {
                v.x = (t     < Tn) ? xb[(size_t)c * Tn + t]     : 0.f;
                v.y = (t + 1 < Tn) ? xb[(size_t)c * Tn + t + 1] : 0.f;
                v.z = (t + 2 < Tn) ? xb[(size_t)c * Tn + t + 2] : 0.f;
                v.w = (t + 3 < Tn) ? xb[(size_t)c * Tn + t + 3] : 0.f;
            }
            unsigned short h0 = f2bf(v.x), h1 = f2bf(v.y);
            unsigned short h2 = f2bf(v.z), h3 = f2bf(v.w);
            xT[(4 * tf + 0) * XT_P + c] = h0;
            xT[(4 * tf + 1) * XT_P + c] = h1;
            xT[(4 * tf + 2) * XT_P + c] = h2;
            xT[(4 * tf + 3) * XT_P + c] = h3;
            *(ushort4*)(xc + c * XC_P + 4 * tf) = make_ushort4(h0, h1, h2, h3);
            s0 = fmaf(v.x, v.x, s0);
            s1 = fmaf(v.y, v.y, s1);
            s2 = fmaf(v.z, v.z, s2);
            s3 = fmaf(v.w, v.w, s3);
        }
        float* xp = xsqp + cg * 33 + 4 * tf;
        xp[0] = s0; xp[1] = s1; xp[2] = s2; xp[3] = s3;
    }
    __syncthreads();

    // --- exact fp32 xsq[t] reduction (wave-0 front; overlaps M-GEMM) ---
    if (tid < 32) {
        float a = 0.f;
#pragma unroll
        for (int g = 0; g < 64; ++g) a += xsqp[g * 33 + tid];
        xsq[tid] = a;
    }

    // --- M-GEMM: wave -> (k-tile = wave>>1, t-tile = wave&1) ---
    {
        const int kt    = wave >> 1;
        const int tt    = wave & 1;
        const int kglob = kt * 16 + n;
        const float* cod = codes + (size_t)(q * 8) * Kn + kglob;  // codes[c][k]
        float csq_part = 0.f;
        f32x4 acc = {0.f, 0.f, 0.f, 0.f};
#pragma unroll
        for (int c0 = 0; c0 < Cn; c0 += 32) {
            float cf[8];
#pragma unroll
            for (int j = 0; j < 8; ++j) cf[j] = cod[(size_t)(c0 + j) * Kn];
            BF8 aF;
#pragma unroll
            for (int j = 0; j < 8; ++j) {
                csq_part = fmaf(cf[j], cf[j], csq_part);
                aF.u[j] = f2bf(cf[j]);
            }
            bf16x8 bF = *(const bf16x8*)(xT + (tt * 16 + n) * XT_P + c0 + q * 8);
            acc = __builtin_amdgcn_mfma_f32_16x16x32_bf16(aF.v, bF, acc, 0, 0, 0);
        }
        csq_part += __shfl_xor(csq_part, 16, 64);
        csq_part += __shfl_xor(csq_part, 32, 64);
        if (tt == 0 && q == 0) csqs[kglob] = csq_part;
#pragma unroll
        for (int r = 0; r < 4; ++r)
            Mw[(kt * 16 + q * 4 + r) * MW_P + tt * 16 + n] = acc[r];
    }
    __syncthreads();

    // --- softmax over k (lane = k); wave handles t = 4*wave..+3 ---
    {
        const float cq = csqs[lane];
        float sp = 0.f;
#pragma unroll
        for (int j = 0; j < 4; ++j) {
            int t = 4 * wave + j;
            float m     = Mw[lane * MW_P + t];
            float logit = -sc * (xsq[t] - 2.f * m + cq);
            float mx = logit;
#pragma unroll
            for (int off = 32; off >= 1; off >>= 1)
                mx = fmaxf(mx, __shfl_xor(mx, off, 64));
            float e = __expf(logit - mx);
            float s = e;
#pragma unroll
            for (int off = 32; off >= 1; off >>= 1)
                s += __shfl_xor(s, off, 64);
            float wv = e / s;
            if (t0 + t >= Tn) wv = 0.f;
            sp += wv;
            wl[lane * WL_P + t] = f2bf(wv);
        }
        spw[wave * 64 + lane] = sp;
    }
    __syncthreads();

    if (tid < 64) {
        float s = 0.f;
#pragma unroll
        for (int w = 0; w < 8; ++w) s += spw[w * 64 + tid];
        Sp[((size_t)b * Kn + tid) * NCH + ch] = s;
    }

    // --- pool: wave -> (k-tile = wave>>1, c-half = wave&1); K = 32 = CH ---
    {
        const int kt    = wave >> 1;
        const int chalf = (wave & 1) * 128;
        bf16x8 aF = *(const bf16x8*)(wl + (kt * 16 + n) * WL_P + q * 8);
        float* pb0 = part + ((size_t)(b * NCH + ch) * Kn + kt * 16 + q * 4) * Cn;
#pragma unroll
        for (int s = 0; s < 8; ++s) {
            int cc = chalf + s * 16;
            bf16x8 bF = *(const bf16x8*)(xc + (cc + n) * XC_P + q * 8);
            f32x4 acc = {0.f, 0.f, 0.f, 0.f};
            acc = __builtin_amdgcn_mfma_f32_16x16x32_bf16(aF, bF, acc, 0, 0, 0);
#pragma unroll
            for (int r = 0; r < 4; ++r)
                pb0[(size_t)r * Cn + cc + n] = acc[r];
        }
    }

    // ======================= grid-wide barrier =======================
    cg::this_grid().sync();

    // --- phase 2: finish. Block handles pairs bk = 2*bid + (tid>>8). ---
    {
        const int h  = tid >> 8;             // 0/1: which (b,k) pair
        const int c  = tid & 255;
        const int bk = 2 * (int)blockIdx.x + h;
        const int b2 = bk >> 6;
        const int k2 = bk & 63;
        const int l  = tid & 63;

        // S = sum_ch Sp[bk, ch] (wave-redundant, no LDS needed)
        float s = (l < NCH) ? Sp[(size_t)bk * NCH + l] : 0.f;
#pragma unroll
        for (int off = 32; off >= 1; off >>= 1) s += __shfl_xor(s, off, 64);
        const float S = s;

        const float* pb = part + ((size_t)b2 * NCH * Kn + k2) * Cn + c;
        float val = 0.f;
#pragma unroll
        for (int ch2 = 0; ch2 < NCH; ++ch2) val += pb[(size_t)ch2 * Kn * Cn];

        float e = (val - codes[c * Kn + k2] * S) * (1.0f / (float)Tn);

        float qq = e * e;
#pragma unroll
        for (int off = 32; off >= 1; off >>= 1) qq += __shfl_xor(qq, off, 64);
        if (l == 0) red2[tid >> 6] = qq;     // one slot per wave (0..7)
        __syncthreads();
        const int hw = h * 4;
        float nn = sqrtf(red2[hw] + red2[hw + 1] + red2[hw + 2] + red2[hw + 3]);

        out[(size_t)bk * Cn + c] = e / fmaxf(nn, 1e-12f);
    }
}

extern "C" void kernel_launch(void* const* d_in, const int* in_sizes, int n_in,
                              void* d_out, int out_size, void* d_ws, size_t ws_size,
                              hipStream_t stream) {
    const float* x      = (const float*)d_in[0];   // (B, C, T) f32
    const float* codes  = (const float*)d_in[1];   // (C, K)    f32
    const float* scales = (const float*)d_in[2];   // (K)       f32
    float* out = (float*)d_out;                    // (B, K, C) f32

    char* ws = (char*)d_ws;
    float* part = (float*)ws;                      // 16 MB: (B, NCH, K, C) f32
    float* Sp   = (float*)(ws + (16u << 20));      // 64 KB: (B, K, NCH) f32

    void* args[] = { (void*)&x, (void*)&codes, (void*)&scales,
                     (void*)&part, (void*)&Sp, (void*)&out };
    hipLaunchCooperativeKernel((void*)lde_all, dim3(Bn * NCH), dim3(512),
                               args, 0, stream);
}

// Round 5
// 78.301 us; speedup vs baseline: 1.6086x; 1.6086x over previous
//
#include <hip/hip_runtime.h>
#include <stdint.h>

// Problem constants: B=8, C=256, K=64, T=1000
constexpr int Bn  = 8;
constexpr int Cn  = 256;
constexpr int Kn  = 64;
constexpr int Tn  = 1000;
constexpr int CH  = 32;    // t per block (T padded to 1024)
constexpr int NCH = 32;    // chunks per b

constexpr int XT_P = 264;  // xT[t][c]  bf16 pitch (rows 16B-aligned)
constexpr int XC_P = 40;   // xc[c][t]  bf16 pitch (rows 16B-aligned)
constexpr int MW_P = 33;   // Mw[k][t]  f32 pitch (bank-friendly)
constexpr int WL_P = 40;   // wl[k][t]  bf16 pitch

typedef float f32x4 __attribute__((ext_vector_type(4)));
typedef __bf16 bf16x8 __attribute__((ext_vector_type(8)));

__device__ __forceinline__ unsigned short f2bf(float f) {
    unsigned u = __float_as_uint(f);
    return (unsigned short)((u + 0x7FFFu + ((u >> 16) & 1u)) >> 16);  // RNE
}

// ---------------------------------------------------------------------------
// Prep (once): codesT[k][c] = bf16(codes[c][k]), csqg[k] = sum_c codes^2.
// 64 blocks (one per k) x 256 thr (one per c). Tiny; L2-resident source.
// ---------------------------------------------------------------------------
__global__ __launch_bounds__(256) void lde_prep(
    const float* __restrict__ codes,        // (C, K)
    unsigned short* __restrict__ codesT,    // (K, C) bf16
    float* __restrict__ csqg)               // (K)
{
    const int k    = blockIdx.x;
    const int c    = threadIdx.x;
    const int lane = c & 63;
    const int wave = c >> 6;
    __shared__ float r4[4];

    float v = codes[(size_t)c * Kn + k];
    codesT[(size_t)k * Cn + c] = f2bf(v);
    float qq = v * v;
#pragma unroll
    for (int off = 32; off >= 1; off >>= 1) qq += __shfl_xor(qq, off, 64);
    if (lane == 0) r4[wave] = qq;
    __syncthreads();
    if (c == 0) csqg[k] = r4[0] + r4[1] + r4[2] + r4[3];
}

// ---------------------------------------------------------------------------
// Fused weights + pool: grid (b x 32 chunks of 32t) = 256 blocks, 512 thr
// (8 waves). Static LDS = 61.6 KB (< 64 KB). Per block:
//   stage: all 8 waves stage x f32->bf16 into xT[t][c] AND xc[c][t]
//          (+ exact fp32 xsq partials from the same registers).
//   M-GEMM: wave -> (k-tile = wave>>1, t-tile = wave&1).
//          A-operand: bf16x8 coalesced loads from codesT (L2/L3-hot, built
//          once by lde_prep — replaces 64 strided scalar loads + 64 f2bf
//          + 64 fmaf per lane of the previous version).
//   softmax over k (lane = k), fp32 (csq from csqg); w -> wl bf16 + Sp.
//   pool: one mfma 16x16x32 contracts the whole 32-t chunk per 16x16 tile:
//         part[b,ch,k,c] = sum_t w[k,t] x[c,t].
// ---------------------------------------------------------------------------
__global__ __launch_bounds__(512, 2) void lde_wp(
    const float* __restrict__ x,            // (B, C, T)
    const unsigned short* __restrict__ codesT, // (K, C) bf16
    const float* __restrict__ csqg,         // (K)
    const float* __restrict__ scales,       // (K)
    float* __restrict__ part,               // (B, NCH, K, C)
    float* __restrict__ Sp)                 // (B, K, NCH)
{
    __shared__ __align__(16) unsigned short xT[CH * XT_P];   // 16896 B
    __shared__ __align__(16) unsigned short xc[Cn * XC_P];   // 20480 B
    __shared__ __align__(16) unsigned short wl[Kn * WL_P];   //  5120 B
    __shared__ float Mw[Kn * MW_P];                          //  8448 B
    __shared__ float xsqp[64 * 33];                          //  8448 B
    __shared__ float xsq[CH];                                //   128 B
    __shared__ float spw[8 * 64];                            //  2048 B

    const int tid  = threadIdx.x;
    const int wave = tid >> 6;
    const int lane = tid & 63;
    const int n    = lane & 15;
    const int q    = lane >> 4;
    const int b    = blockIdx.x >> 5;
    const int ch   = blockIdx.x & 31;
    const int t0   = ch * CH;
    const float sc = scales[lane];           // lane = k in softmax phase

    // --- x staging: 512 threads, thread = (cg, tf); c = cg + 64r ---
    {
        const int tf = tid & 7;              // t-quad: t = t0 + 4*tf + i
        const int cg = tid >> 3;             // 0..63
        const float* xb = x + (size_t)b * Cn * Tn;
        float s0 = 0.f, s1 = 0.f, s2 = 0.f, s3 = 0.f;
        const int t = t0 + 4 * tf;
#pragma unroll
        for (int r = 0; r < 4; ++r) {
            int c = cg + 64 * r;
            float4 v;
            if (t + 3 < Tn) {
                v = *(const float4*)(xb + (size_t)c * Tn + t);
            } else {
                v.x = (t     < Tn) ? xb[(size_t)c * Tn + t]     : 0.f;
                v.y = (t + 1 < Tn) ? xb[(size_t)c * Tn + t + 1] : 0.f;
                v.z = (t + 2 < Tn) ? xb[(size_t)c * Tn + t + 2] : 0.f;
                v.w = (t + 3 < Tn) ? xb[(size_t)c * Tn + t + 3] : 0.f;
            }
            unsigned short h0 = f2bf(v.x), h1 = f2bf(v.y);
            unsigned short h2 = f2bf(v.z), h3 = f2bf(v.w);
            xT[(4 * tf + 0) * XT_P + c] = h0;
            xT[(4 * tf + 1) * XT_P + c] = h1;
            xT[(4 * tf + 2) * XT_P + c] = h2;
            xT[(4 * tf + 3) * XT_P + c] = h3;
            *(ushort4*)(xc + c * XC_P + 4 * tf) = make_ushort4(h0, h1, h2, h3);
            s0 = fmaf(v.x, v.x, s0);
            s1 = fmaf(v.y, v.y, s1);
            s2 = fmaf(v.z, v.z, s2);
            s3 = fmaf(v.w, v.w, s3);
        }
        float* xp = xsqp + cg * 33 + 4 * tf;
        xp[0] = s0; xp[1] = s1; xp[2] = s2; xp[3] = s3;
    }
    __syncthreads();

    // --- exact fp32 xsq[t] reduction (wave-0 front; overlaps M-GEMM) ---
    if (tid < 32) {
        float a = 0.f;
#pragma unroll
        for (int g = 0; g < 64; ++g) a += xsqp[g * 33 + tid];
        xsq[tid] = a;
    }

    // --- M-GEMM: wave -> (k-tile = wave>>1, t-tile = wave&1) ---
    {
        const int kt    = wave >> 1;
        const int tt    = wave & 1;
        const int kglob = kt * 16 + n;
        const unsigned short* codT = codesT + (size_t)kglob * Cn;  // row k
        f32x4 acc = {0.f, 0.f, 0.f, 0.f};
#pragma unroll
        for (int c0 = 0; c0 < Cn; c0 += 32) {
            bf16x8 aF = *(const bf16x8*)(codT + c0 + q * 8);
            bf16x8 bF = *(const bf16x8*)(xT + (tt * 16 + n) * XT_P + c0 + q * 8);
            acc = __builtin_amdgcn_mfma_f32_16x16x32_bf16(aF, bF, acc, 0, 0, 0);
        }
#pragma unroll
        for (int r = 0; r < 4; ++r)
            Mw[(kt * 16 + q * 4 + r) * MW_P + tt * 16 + n] = acc[r];
    }
    __syncthreads();

    // --- softmax over k (lane = k); wave handles t = 4*wave..+3 ---
    {
        const float cq = csqg[lane];
        float sp = 0.f;
#pragma unroll
        for (int j = 0; j < 4; ++j) {
            int t = 4 * wave + j;
            float m     = Mw[lane * MW_P + t];
            float logit = -sc * (xsq[t] - 2.f * m + cq);
            float mx = logit;
#pragma unroll
            for (int off = 32; off >= 1; off >>= 1)
                mx = fmaxf(mx, __shfl_xor(mx, off, 64));
            float e = __expf(logit - mx);
            float s = e;
#pragma unroll
            for (int off = 32; off >= 1; off >>= 1)
                s += __shfl_xor(s, off, 64);
            float wv = e / s;
            if (t0 + t >= Tn) wv = 0.f;
            sp += wv;
            wl[lane * WL_P + t] = f2bf(wv);
        }
        spw[wave * 64 + lane] = sp;
    }
    __syncthreads();

    if (tid < 64) {
        float s = 0.f;
#pragma unroll
        for (int w = 0; w < 8; ++w) s += spw[w * 64 + tid];
        Sp[((size_t)b * Kn + tid) * NCH + ch] = s;
    }

    // --- pool: wave -> (k-tile = wave>>1, c-half = wave&1); K = 32 = CH ---
    {
        const int kt    = wave >> 1;
        const int chalf = (wave & 1) * 128;
        bf16x8 aF = *(const bf16x8*)(wl + (kt * 16 + n) * WL_P + q * 8);
        float* pb0 = part + ((size_t)(b * NCH + ch) * Kn + kt * 16 + q * 4) * Cn;
#pragma unroll
        for (int s = 0; s < 8; ++s) {
            int cc = chalf + s * 16;
            bf16x8 bF = *(const bf16x8*)(xc + (cc + n) * XC_P + q * 8);
            f32x4 acc = {0.f, 0.f, 0.f, 0.f};
            acc = __builtin_amdgcn_mfma_f32_16x16x32_bf16(aF, bF, acc, 0, 0, 0);
#pragma unroll
            for (int r = 0; r < 4; ++r)
                pb0[(size_t)r * Cn + cc + n] = acc[r];
        }
    }
}

// ---------------------------------------------------------------------------
// Finish: block per (b,k), 256 thr = c. Sum 32 chunk-partials, subtract
// codes*S, scale 1/T, l2-normalize over c.
// ---------------------------------------------------------------------------
__global__ __launch_bounds__(256) void lde_fin(
    const float* __restrict__ part,    // (B, NCH, K, C)
    const float* __restrict__ Sp,      // (B, K, NCH)
    const float* __restrict__ codes,   // (C, K)
    float* __restrict__ out)           // (B, K, C)
{
    const int b    = blockIdx.x >> 6;
    const int k    = blockIdx.x & 63;
    const int tid  = threadIdx.x;
    const int lane = tid & 63;
    const int wave = tid >> 6;

    __shared__ float red[4];
    __shared__ float Ss;

    if (wave == 0) {
        float s = (lane < NCH) ? Sp[((size_t)b * Kn + k) * NCH + lane] : 0.f;
#pragma unroll
        for (int off = 32; off >= 1; off >>= 1) s += __shfl_xor(s, off, 64);
        if (lane == 0) Ss = s;
    }
    __syncthreads();
    const float S = Ss;

    const int c = tid;
    const float* pb = part + (size_t)b * NCH * Kn * Cn + (size_t)k * Cn + c;
    float val = 0.f;
#pragma unroll
    for (int chn = 0; chn < NCH; ++chn) val += pb[(size_t)chn * Kn * Cn];

    float e = (val - codes[c * Kn + k] * S) * (1.0f / (float)Tn);

    float qq = e * e;
#pragma unroll
    for (int off = 32; off >= 1; off >>= 1) qq += __shfl_xor(qq, off, 64);
    if (lane == 0) red[wave] = qq;
    __syncthreads();
    float nn = sqrtf(red[0] + red[1] + red[2] + red[3]);

    out[((size_t)b * Kn + k) * Cn + c] = e / fmaxf(nn, 1e-12f);
}

extern "C" void kernel_launch(void* const* d_in, const int* in_sizes, int n_in,
                              void* d_out, int out_size, void* d_ws, size_t ws_size,
                              hipStream_t stream) {
    const float* x      = (const float*)d_in[0];   // (B, C, T) f32
    const float* codes  = (const float*)d_in[1];   // (C, K)    f32
    const float* scales = (const float*)d_in[2];   // (K)       f32
    float* out = (float*)d_out;                    // (B, K, C) f32

    char* ws = (char*)d_ws;
    float*          part   = (float*)ws;                            // 16 MB
    float*          Sp     = (float*)(ws + (16u << 20));            // 64 KB
    unsigned short* codesT = (unsigned short*)(ws + (16u << 20) + (64u << 10)); // 32 KB
    float*          csqg   = (float*)(ws + (16u << 20) + (96u << 10));          // 256 B

    lde_prep<<<Kn,       256, 0, stream>>>(codes, codesT, csqg);
    lde_wp  <<<Bn * NCH, 512, 0, stream>>>(x, codesT, csqg, scales, part, Sp);
    lde_fin <<<Bn * Kn,  256, 0, stream>>>(part, Sp, codes, out);
}

// Round 6
// 77.736 us; speedup vs baseline: 1.6203x; 1.0073x over previous
//
#include <hip/hip_runtime.h>
#include <stdint.h>

// Problem constants: B=8, C=256, K=64, T=1000
constexpr int Bn  = 8;
constexpr int Cn  = 256;
constexpr int Kn  = 64;
constexpr int Tn  = 1000;
constexpr int CH  = 32;    // t per chunk (T padded to 1024)
constexpr int NCH = 32;    // chunks per b

constexpr int XT_P = 264;  // xT[t][c]  bf16 pitch (rows 16B-aligned)
constexpr int XC_P = 40;   // xc[c][t]  bf16 pitch
constexpr int MW_P = 33;   // Mw[k][t]  f32 pitch (bank-friendly)
constexpr int WL_P = 40;   // wl[k][t]  bf16 pitch

typedef float f32x4 __attribute__((ext_vector_type(4)));
typedef __bf16 bf16x8 __attribute__((ext_vector_type(8)));

__device__ __forceinline__ unsigned short f2bf(float f) {
    unsigned u = __float_as_uint(f);
    return (unsigned short)((u + 0x7FFFu + ((u >> 16) & 1u)) >> 16);  // RNE
}

union BF8 { unsigned short u[8]; bf16x8 v; };

// ---------------------------------------------------------------------------
// Fused weights + pool, 2 blocks per chunk (c-split pool): grid 512 blocks x
// 256 thr (4 waves). LDS = 46.3 KB -> 2-3 independent blocks/CU co-resident,
// so one block's MFMA/load phases hide another's softmax/barrier stalls
// (R2's 1-block/CU layout serialized all phases CU-wide).
// bid swizzle: the two half-blocks of a chunk land on the SAME XCD
// (bid and bid+8 share bid&7), so the second block's x-tile reads L2-hit.
//   stage: all 4 waves stage x f32->bf16 into xT[t][c] (full c, for M) and
//          xc[c-local][t] (own 128-c half, for pool) + fp32 xsq partials.
//   M-GEMM: wave = k-tile (4), both t-tiles; A = codes fp32 direct from
//          global (L2-hot, R2-verified pattern) -> bf16 in-register + exact
//          fp32 csq; B from xT.
//   softmax over k (lane = k), fp32, 8 t per wave; w -> wl bf16 + Sp(half0).
//   pool: one mfma per 16x16 tile contracts the 32-t chunk over own c-half:
//         part[b,ch,k,c] = sum_t w[k,t] x[c,t].
// ---------------------------------------------------------------------------
__global__ __launch_bounds__(256, 4) void lde_wp(
    const float* __restrict__ x,            // (B, C, T)
    const float* __restrict__ codes,        // (C, K)
    const float* __restrict__ scales,       // (K)
    float* __restrict__ part,               // (B, NCH, K, C)
    float* __restrict__ Sp)                 // (B, K, NCH)
{
    __shared__ __align__(16) unsigned short xT[CH * XT_P];   // 16896 B
    __shared__ __align__(16) unsigned short xc[128 * XC_P];  // 10240 B
    __shared__ __align__(16) unsigned short wl[Kn * WL_P];   //  5120 B
    __shared__ float Mw[Kn * MW_P];                          //  8448 B
    __shared__ float xsqp[32 * 33];                          //  4224 B
    __shared__ float xsq[CH];                                //   128 B
    __shared__ float csqs[Kn];                               //   256 B
    __shared__ float spw[4 * 64];                            //  1024 B

    const int tid  = threadIdx.x;
    const int wave = tid >> 6;               // 0..3 = k-tile
    const int lane = tid & 63;
    const int n    = lane & 15;
    const int q    = lane >> 4;

    // bid -> (chunk, half) with same-XCD pairing: bid and bid^8 share bid&7.
    const int bid   = (int)blockIdx.x;
    const int xcd   = bid & 7;
    const int half  = (bid >> 3) & 1;
    const int chunk = (bid >> 4) * 8 + xcd;  // 0..255
    const int b     = chunk >> 5;
    const int ch    = chunk & 31;
    const int t0    = ch * CH;
    const float sc  = scales[lane];          // lane = k in softmax phase

    // --- x staging: 256 threads, thread = (cg, tf); c = cg + 32r ---
    {
        const int tf = tid & 7;              // t-quad: t = t0 + 4*tf + i
        const int cg = tid >> 3;             // 0..31
        const float* xb = x + (size_t)b * Cn * Tn;
        float s0 = 0.f, s1 = 0.f, s2 = 0.f, s3 = 0.f;
        const int t = t0 + 4 * tf;
#pragma unroll
        for (int r = 0; r < 8; ++r) {
            int c = cg + 32 * r;
            float4 v;
            if (t + 3 < Tn) {
                v = *(const float4*)(xb + (size_t)c * Tn + t);
            } else {
                v.x = (t     < Tn) ? xb[(size_t)c * Tn + t]     : 0.f;
                v.y = (t + 1 < Tn) ? xb[(size_t)c * Tn + t + 1] : 0.f;
                v.z = (t + 2 < Tn) ? xb[(size_t)c * Tn + t + 2] : 0.f;
                v.w = (t + 3 < Tn) ? xb[(size_t)c * Tn + t + 3] : 0.f;
            }
            unsigned short h0 = f2bf(v.x), h1 = f2bf(v.y);
            unsigned short h2 = f2bf(v.z), h3 = f2bf(v.w);
            xT[(4 * tf + 0) * XT_P + c] = h0;
            xT[(4 * tf + 1) * XT_P + c] = h1;
            xT[(4 * tf + 2) * XT_P + c] = h2;
            xT[(4 * tf + 3) * XT_P + c] = h3;
            if ((r >> 2) == half) {          // own c-half -> xc (uniform per r)
                int cl = cg + 32 * (r & 3);  // 0..127
                *(ushort4*)(xc + cl * XC_P + 4 * tf) =
                    make_ushort4(h0, h1, h2, h3);
            }
            s0 = fmaf(v.x, v.x, s0);
            s1 = fmaf(v.y, v.y, s1);
            s2 = fmaf(v.z, v.z, s2);
            s3 = fmaf(v.w, v.w, s3);
        }
        float* xp = xsqp + cg * 33 + 4 * tf;
        xp[0] = s0; xp[1] = s1; xp[2] = s2; xp[3] = s3;
    }
    __syncthreads();

    // --- exact fp32 xsq[t] reduction (wave-0 front; overlaps M-GEMM) ---
    if (tid < 32) {
        float a = 0.f;
#pragma unroll
        for (int g = 0; g < 32; ++g) a += xsqp[g * 33 + tid];
        xsq[tid] = a;
    }

    // --- M-GEMM: wave = k-tile, both t-tiles ---
    {
        const int kt    = wave;
        const int kglob = kt * 16 + n;
        const float* cod = codes + (size_t)(q * 8) * Kn + kglob;  // codes[c][k]
        float csq_part = 0.f;
        f32x4 acc0 = {0.f, 0.f, 0.f, 0.f};
        f32x4 acc1 = {0.f, 0.f, 0.f, 0.f};
#pragma unroll
        for (int c0 = 0; c0 < Cn; c0 += 32) {
            float cf[8];
#pragma unroll
            for (int j = 0; j < 8; ++j) cf[j] = cod[(size_t)(c0 + j) * Kn];
            BF8 aF;
#pragma unroll
            for (int j = 0; j < 8; ++j) {
                csq_part = fmaf(cf[j], cf[j], csq_part);
                aF.u[j] = f2bf(cf[j]);
            }
            bf16x8 b0 = *(const bf16x8*)(xT + n * XT_P + c0 + q * 8);
            bf16x8 b1 = *(const bf16x8*)(xT + (16 + n) * XT_P + c0 + q * 8);
            acc0 = __builtin_amdgcn_mfma_f32_16x16x32_bf16(aF.v, b0, acc0, 0, 0, 0);
            acc1 = __builtin_amdgcn_mfma_f32_16x16x32_bf16(aF.v, b1, acc1, 0, 0, 0);
        }
        csq_part += __shfl_xor(csq_part, 16, 64);
        csq_part += __shfl_xor(csq_part, 32, 64);
        if (q == 0) csqs[kglob] = csq_part;
#pragma unroll
        for (int r = 0; r < 4; ++r) {
            Mw[(kt * 16 + q * 4 + r) * MW_P + n]      = acc0[r];
            Mw[(kt * 16 + q * 4 + r) * MW_P + 16 + n] = acc1[r];
        }
    }
    __syncthreads();

    // --- softmax over k (lane = k); wave handles t = 8*wave..+7 ---
    {
        const float cq = csqs[lane];
        float sp = 0.f;
#pragma unroll
        for (int j = 0; j < 8; ++j) {
            int t = 8 * wave + j;
            float m     = Mw[lane * MW_P + t];
            float logit = -sc * (xsq[t] - 2.f * m + cq);
            float mx = logit;
#pragma unroll
            for (int off = 32; off >= 1; off >>= 1)
                mx = fmaxf(mx, __shfl_xor(mx, off, 64));
            float e = __expf(logit - mx);
            float s = e;
#pragma unroll
            for (int off = 32; off >= 1; off >>= 1)
                s += __shfl_xor(s, off, 64);
            float wv = e / s;
            if (t0 + t >= Tn) wv = 0.f;
            sp += wv;
            wl[lane * WL_P + t] = f2bf(wv);
        }
        spw[wave * 64 + lane] = sp;
    }
    __syncthreads();

    if (half == 0 && tid < 64) {
        float s = spw[tid] + spw[64 + tid] + spw[128 + tid] + spw[192 + tid];
        Sp[((size_t)b * Kn + tid) * NCH + ch] = s;
    }

    // --- pool: wave = k-tile, own 128-c half; K = 32 = CH per mfma ---
    {
        const int kt = wave;
        bf16x8 aF = *(const bf16x8*)(wl + (kt * 16 + n) * WL_P + q * 8);
        float* pb0 = part + ((size_t)(b * NCH + ch) * Kn + kt * 16 + q * 4) * Cn
                   + half * 128;
#pragma unroll
        for (int s = 0; s < 8; ++s) {
            bf16x8 bF = *(const bf16x8*)(xc + (s * 16 + n) * XC_P + q * 8);
            f32x4 acc = {0.f, 0.f, 0.f, 0.f};
            acc = __builtin_amdgcn_mfma_f32_16x16x32_bf16(aF, bF, acc, 0, 0, 0);
#pragma unroll
            for (int r = 0; r < 4; ++r)
                pb0[(size_t)r * Cn + s * 16 + n] = acc[r];
        }
    }
}

// ---------------------------------------------------------------------------
// Finish: block per (b,k), 256 thr = c. Sum 32 chunk-partials, subtract
// codes*S, scale 1/T, l2-normalize over c.
// ---------------------------------------------------------------------------
__global__ __launch_bounds__(256) void lde_fin(
    const float* __restrict__ part,    // (B, NCH, K, C)
    const float* __restrict__ Sp,      // (B, K, NCH)
    const float* __restrict__ codes,   // (C, K)
    float* __restrict__ out)           // (B, K, C)
{
    const int b    = blockIdx.x >> 6;
    const int k    = blockIdx.x & 63;
    const int tid  = threadIdx.x;
    const int lane = tid & 63;
    const int wave = tid >> 6;

    __shared__ float red[4];
    __shared__ float Ss;

    if (wave == 0) {
        float s = (lane < NCH) ? Sp[((size_t)b * Kn + k) * NCH + lane] : 0.f;
#pragma unroll
        for (int off = 32; off >= 1; off >>= 1) s += __shfl_xor(s, off, 64);
        if (lane == 0) Ss = s;
    }
    __syncthreads();
    const float S = Ss;

    const int c = tid;
    const float* pb = part + (size_t)b * NCH * Kn * Cn + (size_t)k * Cn + c;
    float val = 0.f;
#pragma unroll
    for (int chn = 0; chn < NCH; ++chn) val += pb[(size_t)chn * Kn * Cn];

    float e = (val - codes[c * Kn + k] * S) * (1.0f / (float)Tn);

    float qq = e * e;
#pragma unroll
    for (int off = 32; off >= 1; off >>= 1) qq += __shfl_xor(qq, off, 64);
    if (lane == 0) red[wave] = qq;
    __syncthreads();
    float nn = sqrtf(red[0] + red[1] + red[2] + red[3]);

    out[((size_t)b * Kn + k) * Cn + c] = e / fmaxf(nn, 1e-12f);
}

extern "C" void kernel_launch(void* const* d_in, const int* in_sizes, int n_in,
                              void* d_out, int out_size, void* d_ws, size_t ws_size,
                              hipStream_t stream) {
    const float* x      = (const float*)d_in[0];   // (B, C, T) f32
    const float* codes  = (const float*)d_in[1];   // (C, K)    f32
    const float* scales = (const float*)d_in[2];   // (K)       f32
    float* out = (float*)d_out;                    // (B, K, C) f32

    char* ws = (char*)d_ws;
    float* part = (float*)ws;                      // 16 MB: (B, NCH, K, C) f32
    float* Sp   = (float*)(ws + (16u << 20));      // 64 KB: (B, K, NCH) f32

    lde_wp <<<2 * Bn * NCH, 256, 0, stream>>>(x, codes, scales, part, Sp);
    lde_fin<<<Bn * Kn,      256, 0, stream>>>(part, Sp, codes, out);
}

// Round 7
// 75.238 us; speedup vs baseline: 1.6741x; 1.0332x over previous
//
#include <hip/hip_runtime.h>
#include <stdint.h>

// Problem constants: B=8, C=256, K=64, T=1000
constexpr int Bn  = 8;
constexpr int Cn  = 256;
constexpr int Kn  = 64;
constexpr int Tn  = 1000;
constexpr int CH  = 16;    // K1 t-chunk (T padded to 1024)
constexpr int NCH = 64;    // chunks per b
constexpr int TW  = 256;   // K2 t-window
constexpr int NTQ = 4;     // windows per b

constexpr int XT_P = 264;  // xT[t][c] bf16 pitch (16B-aligned rows)
constexpr int MW_P = 20;   // Mw[k][t] f32 pitch
constexpr int XC_P = 264;  // K2 xc[c][t] bf16 pitch

typedef float f32x4 __attribute__((ext_vector_type(4)));
typedef __bf16 bf16x8 __attribute__((ext_vector_type(8)));

__device__ __forceinline__ unsigned short f2bf(float f) {
    unsigned u = __float_as_uint(f);
    return (unsigned short)((u + 0x7FFFu + ((u >> 16) & 1u)) >> 16);  // RNE
}

union BF8 { unsigned short u[8]; bf16x8 v; };

// ---------------------------------------------------------------------------
// K1 weights (prep folded in): grid (b x 64 chunks of 16t) = 512 blocks,
// 256 thr (4 waves, 2 waves/SIMD at 2 blocks/CU).
//   A-operand: codes fp32 read strided in fragment order, converted to bf16
//              in-register; csq[k] accumulated exactly in fp32 on the way.
//   B-operand: x staged to LDS bf16 (xT), xsq from the same fp32 registers.
//   M[k,t] via mfma 16x16x32; softmax fp32; out w_g bf16 + Sp f32.
// ---------------------------------------------------------------------------
__global__ __launch_bounds__(256) void lde_w(
    const float* __restrict__ x,            // (B, C, T)
    const float* __restrict__ codes,        // (C, K)
    const float* __restrict__ scales,       // (K)
    unsigned short* __restrict__ w_g,       // (B, NCH, K, CH) bf16
    float* __restrict__ Sp)                 // (B, K, NCH)
{
    __shared__ __align__(16) unsigned short xT[CH * XT_P];  // [t][c] bf16
    __shared__ float Mw[Kn * MW_P];                         // [k][t]
    __shared__ float xsqp[64 * 17];
    __shared__ float xsq[CH];
    __shared__ float csqs[Kn];
    __shared__ float spw[4 * 64];

    const int tid  = threadIdx.x;
    const int wave = tid >> 6;
    const int lane = tid & 63;
    const int n    = lane & 15;
    const int q    = lane >> 4;
    const int b    = blockIdx.x >> 6;
    const int ch   = blockIdx.x & 63;
    const int t0   = ch * CH;
    const float* xb = x + (size_t)b * Cn * Tn;

    // --- stage xT (bf16) + xsq partials from the same fp32 registers ---
    // thread: tf = tid&3 (t-quad) fixed; c = (tid>>2) + 64r.
    {
        const int tf = tid & 3;
        float sq0 = 0.f, sq1 = 0.f, sq2 = 0.f, sq3 = 0.f;
#pragma unroll
        for (int r = 0; r < 4; ++r) {
            int c = (tid >> 2) + 64 * r;
            int t = t0 + 4 * tf;
            float4 v;
            if (t + 3 < Tn) {
                v = *(const float4*)(xb + c * Tn + t);
            } else {
                v.x = (t     < Tn) ? xb[c * Tn + t]     : 0.f;
                v.y = (t + 1 < Tn) ? xb[c * Tn + t + 1] : 0.f;
                v.z = (t + 2 < Tn) ? xb[c * Tn + t + 2] : 0.f;
                v.w = (t + 3 < Tn) ? xb[c * Tn + t + 3] : 0.f;
            }
            xT[(4 * tf + 0) * XT_P + c] = f2bf(v.x);
            xT[(4 * tf + 1) * XT_P + c] = f2bf(v.y);
            xT[(4 * tf + 2) * XT_P + c] = f2bf(v.z);
            xT[(4 * tf + 3) * XT_P + c] = f2bf(v.w);
            sq0 = fmaf(v.x, v.x, sq0);
            sq1 = fmaf(v.y, v.y, sq1);
            sq2 = fmaf(v.z, v.z, sq2);
            sq3 = fmaf(v.w, v.w, sq3);
        }
        float* xp = xsqp + (tid >> 2) * 17 + 4 * tf;
        xp[0] = sq0; xp[1] = sq1; xp[2] = sq2; xp[3] = sq3;
    }
    __syncthreads();

    if (tid < CH) {
        float a = 0.f;
#pragma unroll
        for (int i = 0; i < 64; ++i) a += xsqp[i * 17 + tid];
        xsq[tid] = a;
    }

    // --- M GEMM: wave = k-tile. A from global fp32 codes, converted bf16;
    //     csq[k] exact fp32 along the way. B from LDS xT. ---
    {
        const int kglob = wave * 16 + n;
        const float* cod = codes + (q * 8) * Kn + kglob;  // codes[c][k]
        float csq_part = 0.f;
        f32x4 acc = {0.f, 0.f, 0.f, 0.f};
#pragma unroll
        for (int c0 = 0; c0 < Cn; c0 += 32) {
            float cf[8];
#pragma unroll
            for (int j = 0; j < 8; ++j) cf[j] = cod[(size_t)(c0 + j) * Kn];
            BF8 aF;
#pragma unroll
            for (int j = 0; j < 8; ++j) {
                csq_part = fmaf(cf[j], cf[j], csq_part);
                aF.u[j] = f2bf(cf[j]);
            }
            bf16x8 bF = *(const bf16x8*)(xT + n * XT_P + c0 + q * 8);
            acc = __builtin_amdgcn_mfma_f32_16x16x32_bf16(aF.v, bF, acc, 0, 0, 0);
        }
        csq_part += __shfl_xor(csq_part, 16, 64);
        csq_part += __shfl_xor(csq_part, 32, 64);
        if (q == 0) csqs[kglob] = csq_part;
#pragma unroll
        for (int r = 0; r < 4; ++r)
            Mw[(wave * 16 + q * 4 + r) * MW_P + n] = acc[r];  // col n -> t
    }
    __syncthreads();

    // --- softmax over k (lane = k); wave handles t = wave*4..+3 ---
    {
        const float sc = scales[lane];
        const float cq = csqs[lane];
        unsigned short wh[4];
        float sp = 0.f;
#pragma unroll
        for (int j = 0; j < 4; ++j) {
            int t = wave * 4 + j;
            float m     = Mw[lane * MW_P + t];
            float logit = -sc * (xsq[t] - 2.f * m + cq);
            float mx = logit;
#pragma unroll
            for (int off = 32; off >= 1; off >>= 1)
                mx = fmaxf(mx, __shfl_xor(mx, off, 64));
            float e = __expf(logit - mx);
            float s = e;
#pragma unroll
            for (int off = 32; off >= 1; off >>= 1)
                s += __shfl_xor(s, off, 64);
            float wv = e / s;
            if (t0 + t >= Tn) wv = 0.f;
            sp += wv;
            wh[j] = f2bf(wv);
        }
        *(ushort4*)(w_g + ((size_t)(b * NCH + ch) * Kn + lane) * CH + wave * 4) =
            make_ushort4(wh[0], wh[1], wh[2], wh[3]);
        spw[wave * 64 + lane] = sp;
    }
    __syncthreads();
    if (wave == 0) {
        float s4 = spw[lane] + spw[64 + lane] + spw[128 + lane] + spw[192 + lane];
        Sp[((size_t)b * Kn + lane) * NCH + ch] = s4;
    }
}

// ---------------------------------------------------------------------------
// K2 pool: grid (b x 16 c-tiles x 4 t-windows of 256) = 512 blocks, 4 waves.
//   part[b,tq,k,c] = sum_{t in window} w[k,t] * x[c,t]   (8 mfma / wave)
// ---------------------------------------------------------------------------
__global__ __launch_bounds__(256) void lde_pool(
    const float* __restrict__ x,            // (B, C, T)
    const unsigned short* __restrict__ w_g, // (B, NCH, K, CH) bf16
    float* __restrict__ part)               // (B, NTQ, K, C)
{
    __shared__ __align__(16) unsigned short xc[16 * XC_P];  // [c-local][t-local]

    const int tid  = threadIdx.x;
    const int wave = tid >> 6;            // k-tile
    const int lane = tid & 63;
    const int n    = lane & 15;
    const int q    = lane >> 4;
    const int bid  = blockIdx.x;
    const int b    = bid >> 6;
    const int ct   = (bid >> 2) & 15;
    const int tq   = bid & 3;
    const int c0   = ct * 16;
    const int tw0  = tq * TW;
    const float* xb = x + (size_t)(b * Cn + c0) * Tn;

#pragma unroll
    for (int r = 0; r < 4; ++r) {
        int idx = r * 256 + tid;
        int cl = idx >> 6, tf = idx & 63;
        int t = tw0 + 4 * tf;
        float4 v;
        if (t + 3 < Tn) {
            v = *(const float4*)(xb + cl * Tn + t);
        } else {
            v.x = (t     < Tn) ? xb[cl * Tn + t]     : 0.f;
            v.y = (t + 1 < Tn) ? xb[cl * Tn + t + 1] : 0.f;
            v.z = (t + 2 < Tn) ? xb[cl * Tn + t + 2] : 0.f;
            v.w = (t + 3 < Tn) ? xb[cl * Tn + t + 3] : 0.f;
        }
        *(ushort4*)(xc + cl * XC_P + 4 * tf) =
            make_ushort4(f2bf(v.x), f2bf(v.y), f2bf(v.z), f2bf(v.w));
    }
    __syncthreads();

    f32x4 acc = {0.f, 0.f, 0.f, 0.f};
#pragma unroll
    for (int s = 0; s < 8; ++s) {
        int tg  = tw0 + s * 32 + q * 8;       // global t of this frag
        int chh = tg >> 4;                    // chunk in w_g
        int tl  = tg & 15;                    // 0 or 8
        bf16x8 aF = *(const bf16x8*)(w_g + ((size_t)(b * NCH + chh) * Kn + wave * 16 + n) * CH + tl);
        bf16x8 bF = *(const bf16x8*)(xc + n * XC_P + s * 32 + q * 8);
        acc = __builtin_amdgcn_mfma_f32_16x16x32_bf16(aF, bF, acc, 0, 0, 0);
    }
    // D: col n -> c, row q*4+r -> k
    float* pb = part + ((size_t)(b * NTQ + tq) * Kn + wave * 16 + q * 4) * Cn + c0 + n;
#pragma unroll
    for (int r = 0; r < 4; ++r)
        pb[(size_t)r * Cn] = acc[r];
}

// ---------------------------------------------------------------------------
// K3 finish: block per (b,k), 256 thr = c.
// ---------------------------------------------------------------------------
__global__ __launch_bounds__(256) void lde_fin(
    const float* __restrict__ part,    // (B, NTQ, K, C)
    const float* __restrict__ Sp,      // (B, K, NCH)
    const float* __restrict__ codes,   // (C, K)
    float* __restrict__ out)           // (B, K, C)
{
    const int b    = blockIdx.x >> 6;
    const int k    = blockIdx.x & 63;
    const int tid  = threadIdx.x;
    const int lane = tid & 63;
    const int wave = tid >> 6;

    __shared__ float red[4];
    __shared__ float Ss;

    if (wave == 0) {
        float s = Sp[((size_t)b * Kn + k) * NCH + lane];   // 256B coalesced
#pragma unroll
        for (int off = 32; off >= 1; off >>= 1) s += __shfl_xor(s, off, 64);
        if (lane == 0) Ss = s;
    }
    __syncthreads();
    const float S = Ss;

    const int c = tid;
    const float* pb = part + (size_t)b * NTQ * Kn * Cn + k * Cn + c;
    float val = pb[0] + pb[(size_t)Kn * Cn] + pb[(size_t)2 * Kn * Cn] + pb[(size_t)3 * Kn * Cn];

    float e = (val - codes[c * Kn + k] * S) * (1.0f / (float)Tn);

    float qq = e * e;
#pragma unroll
    for (int off = 32; off >= 1; off >>= 1) qq += __shfl_xor(qq, off, 64);
    if (lane == 0) red[wave] = qq;
    __syncthreads();
    float nn = sqrtf(red[0] + red[1] + red[2] + red[3]);

    out[((size_t)b * Kn + k) * Cn + c] = e / fmaxf(nn, 1e-12f);
}

extern "C" void kernel_launch(void* const* d_in, const int* in_sizes, int n_in,
                              void* d_out, int out_size, void* d_ws, size_t ws_size,
                              hipStream_t stream) {
    const float* x      = (const float*)d_in[0];   // (B, C, T) f32
    const float* codes  = (const float*)d_in[1];   // (C, K)    f32
    const float* scales = (const float*)d_in[2];   // (K)       f32
    float* out = (float*)d_out;                    // (B, K, C) f32

    char* ws = (char*)d_ws;
    float*          part = (float*)ws;                          // 2 MB
    unsigned short* w_g  = (unsigned short*)(ws + (2u << 20));  // 1 MB
    float*          Sp   = (float*)(ws + (3u << 20));           // 128 KB

    lde_w   <<<Bn * NCH,      256, 0, stream>>>(x, codes, scales, w_g, Sp);
    lde_pool<<<Bn * 16 * NTQ, 256, 0, stream>>>(x, w_g, part);
    lde_fin <<<Bn * Kn,       256, 0, stream>>>(part, Sp, codes, out);
}